// Round 5
// baseline (35.500 us; speedup 1.0000x reference)
//
#include <hip/hip_runtime.h>

#define NEG_SLOPE 0.01f

typedef _Float16 f16;
typedef _Float16 f16x4 __attribute__((ext_vector_type(4)));
typedef float    f32x4 __attribute__((ext_vector_type(4)));

__device__ __forceinline__ float leaky(float v) {
    // 0 < slope < 1  =>  leaky(v) == max(v, slope*v)
    return fmaxf(v, NEG_SLOPE * v);
}

// ws layout (float indices):
//   [0,      8192)    node_out f32            (B*N)
//   [8192,   73728)   pjh  f16[8192][16]      x@Wc1_j          (131072 f16)
//   [73728,  139264)  piuh f16[8192][16]      x@Wc1_i + bc1
//   [139264, 401408)  S    f32[512][512]      sigmoid(A_param), diag=0
#define WS_PJH  8192
#define WS_PIUH 73728
#define WS_S    139264

// ---------------- Kernel 1: node MLP + precompute ----------------
__global__ __launch_bounds__(256) void k1_fused(
    const float* __restrict__ x,
    const float* __restrict__ Wn1, const float* __restrict__ bn1,
    const float* __restrict__ Wn2, const float* __restrict__ bn2,
    const float* __restrict__ Wn3, const float* __restrict__ bn3,
    const float* __restrict__ Wc1, const float* __restrict__ bc1,
    const float* __restrict__ A_param,
    float* __restrict__ ws, float* __restrict__ out)
{
    __shared__ float sh[4][64];
    const int t    = threadIdx.x;
    const int lane = t & 63;
    const int wv   = t >> 6;
    const int row  = blockIdx.x * 4 + wv;   // b*N + n

    const float x0 = x[row * 2 + 0];
    const float x1 = x[row * 2 + 1];

    // node layer 1
    const float h = leaky(fmaf(x0, Wn1[lane], fmaf(x1, Wn1[64 + lane], bn1[lane])));
    sh[wv][lane] = h;
    __syncthreads();

    // fused: sigmoid(A_param) table, diag zeroed (blocks 0..1023 cover 512*512)
    {
        const int g = blockIdx.x * 256 + t;
        if (g < 512 * 512) {
            const int i = g >> 9, j = g & 511;
            const float a = A_param[g];
            float s = __fdividef(1.0f, 1.0f + __expf(-a));
            if (i == j) s = 0.0f;
            ws[WS_S + g] = s;
        }
    }

    // fused: pj / piu rows (f16) for the coupling MLP
    if (lane < 16) {
        f16* pjh  = (f16*)(ws + WS_PJH);
        f16* piuh = (f16*)(ws + WS_PIUH);
        const float pj = fmaf(x0, Wc1[lane], x1 * Wc1[16 + lane]);
        const float pi = fmaf(x0, Wc1[32 + lane], fmaf(x1, Wc1[48 + lane], bc1[lane]));
        pjh [row * 16 + lane] = (f16)pj;
        piuh[row * 16 + lane] = (f16)pi;
    }

    // node layer 2
    float acc = bn2[lane];
    #pragma unroll
    for (int c = 0; c < 64; ++c)
        acc = fmaf(sh[wv][c], Wn2[c * 64 + lane], acc);
    const float h2 = leaky(acc);

    // node layer 3 (64 -> 1)
    float p = h2 * Wn3[lane];
    #pragma unroll
    for (int off = 32; off > 0; off >>= 1)
        p += __shfl_xor(p, off, 64);
    if (lane == 0) {
        ws[row] = p + bn3[0];      // node_out
        out[row * 2 + 0] = x1;     // out0 = x[...,1]
    }
}

// ---------------- Kernel 2: pairwise coupling via MFMA ----------------
// One wave per (b,i). Tile = 16 j's. Lane (p=l&15, c4=(l>>4)*4):
//   b1 = pk_max(s, 0.01*s), s = pjh4[j] + piuh4[i]     (packed f16, 6 instr)
//   d1 = Wc2^T(hi) x b1 + (Wc2^T(lo) x b1 + bc2)       (2 MFMAs, hi/lo exact W)
//   accE[e] += S[i,j] * leaky(d1[e]);  vS += S[i,j]
// Epilogue: pp = accE . w3 + 0.25*b3*vS, butterfly-sum 64 lanes.
__global__ __launch_bounds__(64) void k2_pair_mfma(
    const float* __restrict__ Wc2, const float* __restrict__ bc2,
    const float* __restrict__ Wc3, const float* __restrict__ bc3,
    const float* __restrict__ ws, float* __restrict__ out)
{
    const int l  = threadIdx.x;       // 0..63
    const int p  = l & 15;            // pair slot within tile
    const int c4 = (l >> 4) << 2;     // channel base
    const int bi = blockIdx.x;        // b*512 + i
    const int b  = bi >> 9;
    const int i  = bi & 511;

    const float* node_out = ws;
    const f16*   pjh  = (const f16*)(ws + WS_PJH);
    const f16*   piuh = (const f16*)(ws + WS_PIUH);
    const float* S    = ws + WS_S;

    // Wc2^T fragment, hi/lo split (weight quantization error ~2^-22)
    f16x4 w2hi, w2lo;
    f32x4 c1;                          // C for MFMA: bc2[c4+e]
    float w3[4];
    #pragma unroll
    for (int e = 0; e < 4; ++e) {
        const int c = c4 + e;
        const float w2 = Wc2[c * 16 + p];
        const f16 hw = (f16)w2;
        w2hi[e] = hw; w2lo[e] = (f16)(w2 - (float)hw);
        w3[e] = Wc3[c];
        c1[e] = bc2[c];
    }
    const float b3 = bc3[0];

    const f16x4 piu4 = *reinterpret_cast<const f16x4*>(piuh + bi * 16 + c4);
    const f16x4 slope4 = {(f16)NEG_SLOPE, (f16)NEG_SLOPE, (f16)NEG_SLOPE, (f16)NEG_SLOPE};
    const f16*   pjb = pjh + b * 512 * 16;
    const float* Sr  = S + i * 512;

    float accE[4] = {0.0f, 0.0f, 0.0f, 0.0f};
    float vS = 0.0f;
    #pragma unroll 4
    for (int t = 0; t < 32; ++t) {
        const int j = t * 16 + p;
        const f16x4 pj4 = *reinterpret_cast<const f16x4*>(pjb + j * 16 + c4);

        const f16x4 s4 = pj4 + piu4;                       // 2x v_pk_add_f16
        const f16x4 b1 = __builtin_elementwise_max(s4, s4 * slope4); // pk_mul+pk_max

        f32x4 d1 = __builtin_amdgcn_mfma_f32_16x16x16f16(w2lo, b1, c1, 0, 0, 0);
        d1 = __builtin_amdgcn_mfma_f32_16x16x16f16(w2hi, b1, d1, 0, 0, 0);

        const float Sj = Sr[j];
        vS += Sj;
        #pragma unroll
        for (int e = 0; e < 4; ++e)
            accE[e] = fmaf(fmaxf(d1[e], NEG_SLOPE * d1[e]), Sj, accE[e]);
    }

    float pp = fmaf(accE[0], w3[0],
               fmaf(accE[1], w3[1],
               fmaf(accE[2], w3[2], accE[3] * w3[3])));
    pp = fmaf(0.25f * b3, vS, pp);     // 4-way lane duplication of S -> x0.25

    // sum over 16 pairs x 4 channel groups
    #pragma unroll
    for (int off = 32; off > 0; off >>= 1)
        pp += __shfl_xor(pp, off, 64);

    if (l == 0)
        out[bi * 2 + 1] = node_out[bi] + pp;
}

extern "C" void kernel_launch(void* const* d_in, const int* in_sizes, int n_in,
                              void* d_out, int out_size, void* d_ws, size_t ws_size,
                              hipStream_t stream) {
    const float* x       = (const float*)d_in[0];
    const float* Wn1     = (const float*)d_in[1];
    const float* bn1     = (const float*)d_in[2];
    const float* Wn2     = (const float*)d_in[3];
    const float* bn2     = (const float*)d_in[4];
    const float* Wn3     = (const float*)d_in[5];
    const float* bn3     = (const float*)d_in[6];
    const float* Wc1     = (const float*)d_in[7];
    const float* bc1     = (const float*)d_in[8];
    const float* Wc2     = (const float*)d_in[9];
    const float* bc2     = (const float*)d_in[10];
    const float* Wc3     = (const float*)d_in[11];
    const float* bc3     = (const float*)d_in[12];
    const float* A_param = (const float*)d_in[13];
    float* out = (float*)d_out;
    float* ws  = (float*)d_ws;

    const int BN = 16 * 512;          // 8192 rows

    k1_fused<<<BN / 4, 256, 0, stream>>>(x, Wn1, bn1, Wn2, bn2, Wn3, bn3,
                                         Wc1, bc1, A_param, ws, out);
    k2_pair_mfma<<<BN, 64, 0, stream>>>(Wc2, bc2, Wc3, bc3, ws, out);
}

// Round 6
// 30.031 us; speedup vs baseline: 1.1821x; 1.1821x over previous
//
#include <hip/hip_runtime.h>

#define NEG_SLOPE 0.01f

typedef _Float16 f16;
typedef _Float16 f16x4 __attribute__((ext_vector_type(4)));
typedef float    f32x4 __attribute__((ext_vector_type(4)));

__device__ __forceinline__ float leaky(float v) {
    // 0 < slope < 1  =>  leaky(v) == max(v, slope*v)
    return fmaxf(v, NEG_SLOPE * v);
}

// ws layout (float indices):
//   [0,      8192)    node_out f32            (B*N)
//   [8192,   73728)   pjh  f16[8192][16]      x@Wc1_j
//   [73728,  139264)  piuh f16[8192][16]      x@Wc1_i + bc1
//   [139264, 401408)  S    f32[512][512]      sigmoid(A_param), diag=0
#define WS_PJH  8192
#define WS_PIUH 73728
#define WS_S    139264

// ---------------- Kernel 1: node MLP + precompute ----------------
__global__ __launch_bounds__(256) void k1_fused(
    const float* __restrict__ x,
    const float* __restrict__ Wn1, const float* __restrict__ bn1,
    const float* __restrict__ Wn2, const float* __restrict__ bn2,
    const float* __restrict__ Wn3, const float* __restrict__ bn3,
    const float* __restrict__ Wc1, const float* __restrict__ bc1,
    const float* __restrict__ A_param,
    float* __restrict__ ws, float* __restrict__ out)
{
    __shared__ float sh[4][64];
    const int t    = threadIdx.x;
    const int lane = t & 63;
    const int wv   = t >> 6;
    const int row  = blockIdx.x * 4 + wv;   // b*N + n

    const float x0 = x[row * 2 + 0];
    const float x1 = x[row * 2 + 1];

    // node layer 1
    const float h = leaky(fmaf(x0, Wn1[lane], fmaf(x1, Wn1[64 + lane], bn1[lane])));
    sh[wv][lane] = h;
    __syncthreads();

    // fused: sigmoid(A_param) table, diag zeroed (blocks 0..1023 cover 512*512)
    {
        const int g = blockIdx.x * 256 + t;
        if (g < 512 * 512) {
            const int i = g >> 9, j = g & 511;
            const float a = A_param[g];
            float s = __fdividef(1.0f, 1.0f + __expf(-a));
            if (i == j) s = 0.0f;
            ws[WS_S + g] = s;
        }
    }

    // fused: pj / piu rows (f16) for the coupling MLP
    if (lane < 16) {
        f16* pjh  = (f16*)(ws + WS_PJH);
        f16* piuh = (f16*)(ws + WS_PIUH);
        const float pj = fmaf(x0, Wc1[lane], x1 * Wc1[16 + lane]);
        const float pi = fmaf(x0, Wc1[32 + lane], fmaf(x1, Wc1[48 + lane], bc1[lane]));
        pjh [row * 16 + lane] = (f16)pj;
        piuh[row * 16 + lane] = (f16)pi;
    }

    // node layer 2
    float acc = bn2[lane];
    #pragma unroll
    for (int c = 0; c < 64; ++c)
        acc = fmaf(sh[wv][c], Wn2[c * 64 + lane], acc);
    const float h2 = leaky(acc);

    // node layer 3 (64 -> 1)
    float p = h2 * Wn3[lane];
    #pragma unroll
    for (int off = 32; off > 0; off >>= 1)
        p += __shfl_xor(p, off, 64);
    if (lane == 0) {
        ws[row] = p + bn3[0];      // node_out
        out[row * 2 + 0] = x1;     // out0 = x[...,1]
    }
}

// ---------------- Kernel 2: pairwise coupling via MFMA ----------------
// One 256-thread block per (b,i); 4 waves split the 32 j-tiles (8 each).
// Lane (p=l&15, c4=(l>>4)*4), tile j-range handled fully unrolled:
//   b1 = pk_max(s, 0.01*s), s = pjh4[j] + piuh4[i]     (packed f16)
//   d1 = Wc2^T(hi) x b1 + (Wc2^T(lo) x b1 + bc2)       (2 MFMAs, exact weights)
//   accE[e] += S[i,j]*leaky(d1[e]);  vS += S[i,j]      (S from LDS)
// pp = accE.w3 + 0.25*b3*vS; butterfly(64); LDS reduce over 4 waves.
__global__ __launch_bounds__(256) void k2_pair_mfma(
    const float* __restrict__ Wc2, const float* __restrict__ bc2,
    const float* __restrict__ Wc3, const float* __restrict__ bc3,
    const float* __restrict__ ws, float* __restrict__ out)
{
    __shared__ float sS[512];
    __shared__ float sred[4];

    const int t  = threadIdx.x;
    const int l  = t & 63;            // lane in wave
    const int wv = t >> 6;            // wave 0..3
    const int p  = l & 15;            // pair slot within tile
    const int c4 = (l >> 4) << 2;     // channel base
    const int bi = blockIdx.x;        // b*512 + i
    const int b  = bi >> 9;
    const int i  = bi & 511;

    const float* node_out = ws;
    const f16*   pjh  = (const f16*)(ws + WS_PJH);
    const f16*   piuh = (const f16*)(ws + WS_PIUH);
    const float* S    = ws + WS_S;

    // stage S row (512 f32) into LDS
    sS[t]       = S[i * 512 + t];
    sS[t + 256] = S[i * 512 + t + 256];

    // Wc2^T fragment, hi/lo split (weight quantization error ~2^-22)
    f16x4 w2hi, w2lo;
    f32x4 c1;                          // C for MFMA: bc2[c4+e]
    float w3[4];
    #pragma unroll
    for (int e = 0; e < 4; ++e) {
        const int c = c4 + e;
        const float w2 = Wc2[c * 16 + p];
        const f16 hw = (f16)w2;
        w2hi[e] = hw; w2lo[e] = (f16)(w2 - (float)hw);
        w3[e] = Wc3[c];
        c1[e] = bc2[c];
    }
    const float b3 = bc3[0];

    const f16x4 piu4 = *reinterpret_cast<const f16x4*>(piuh + bi * 16 + c4);
    const f16x4 slope4 = {(f16)NEG_SLOPE, (f16)NEG_SLOPE, (f16)NEG_SLOPE, (f16)NEG_SLOPE};
    const f16* pjb = pjh + b * 512 * 16;

    __syncthreads();

    float accE[4] = {0.0f, 0.0f, 0.0f, 0.0f};
    float vS = 0.0f;
    #pragma unroll
    for (int tt = 0; tt < 8; ++tt) {
        const int j = (wv * 8 + tt) * 16 + p;
        const f16x4 pj4 = *reinterpret_cast<const f16x4*>(pjb + j * 16 + c4);

        const f16x4 s4 = pj4 + piu4;                                 // v_pk_add_f16
        const f16x4 b1 = __builtin_elementwise_max(s4, s4 * slope4); // pk_mul+pk_max

        f32x4 d1 = __builtin_amdgcn_mfma_f32_16x16x16f16(w2lo, b1, c1, 0, 0, 0);
        d1 = __builtin_amdgcn_mfma_f32_16x16x16f16(w2hi, b1, d1, 0, 0, 0);

        const float Sj = sS[j];
        vS += Sj;
        #pragma unroll
        for (int e = 0; e < 4; ++e)
            accE[e] = fmaf(fmaxf(d1[e], NEG_SLOPE * d1[e]), Sj, accE[e]);
    }

    float pp = fmaf(accE[0], w3[0],
               fmaf(accE[1], w3[1],
               fmaf(accE[2], w3[2], accE[3] * w3[3])));
    pp = fmaf(0.25f * b3, vS, pp);     // 4-way lane duplication of S -> x0.25

    // sum over 16 pairs x 4 channel groups within the wave
    #pragma unroll
    for (int off = 32; off > 0; off >>= 1)
        pp += __shfl_xor(pp, off, 64);

    if (l == 0) sred[wv] = pp;
    __syncthreads();

    if (t == 0)
        out[bi * 2 + 1] = node_out[bi] + sred[0] + sred[1] + sred[2] + sred[3];
}

extern "C" void kernel_launch(void* const* d_in, const int* in_sizes, int n_in,
                              void* d_out, int out_size, void* d_ws, size_t ws_size,
                              hipStream_t stream) {
    const float* x       = (const float*)d_in[0];
    const float* Wn1     = (const float*)d_in[1];
    const float* bn1     = (const float*)d_in[2];
    const float* Wn2     = (const float*)d_in[3];
    const float* bn2     = (const float*)d_in[4];
    const float* Wn3     = (const float*)d_in[5];
    const float* bn3     = (const float*)d_in[6];
    const float* Wc1     = (const float*)d_in[7];
    const float* bc1     = (const float*)d_in[8];
    const float* Wc2     = (const float*)d_in[9];
    const float* bc2     = (const float*)d_in[10];
    const float* Wc3     = (const float*)d_in[11];
    const float* bc3     = (const float*)d_in[12];
    const float* A_param = (const float*)d_in[13];
    float* out = (float*)d_out;
    float* ws  = (float*)d_ws;

    const int BN = 16 * 512;          // 8192 rows

    k1_fused<<<BN / 4, 256, 0, stream>>>(x, Wn1, bn1, Wn2, bn2, Wn3, bn3,
                                         Wc1, bc1, A_param, ws, out);
    k2_pair_mfma<<<BN, 256, 0, stream>>>(Wc2, bc2, Wc3, bc3, ws, out);
}